// Round 4
// baseline (101.058 us; speedup 1.0000x reference)
//
#include <hip/hip_runtime.h>
#include <hip/hip_bf16.h>
#include <math.h>

#define Nn 8192
#define Mm 8192
#define DIM 128
#define EPS 0.001
#define NCHUNK 16   // col chunks; each block sweeps 8 j-steps of 64 cols = 512 cols
#define NBAND 256   // 64 row-blocks x 4 waves

typedef __attribute__((ext_vector_type(8))) short bf16x8;
typedef __attribute__((ext_vector_type(4))) float f32x4;
typedef __attribute__((ext_vector_type(4))) float f4;

// ---- prep: bf16 convert + row squared-norms for BOTH x and y in one launch ----
__global__ __launch_bounds__(256) void prep2(const float* __restrict__ X,
    const float* __restrict__ Y, unsigned short* __restrict__ Xb,
    unsigned short* __restrict__ Yb, float* __restrict__ X2, float* __restrict__ Y2) {
  int gid = blockIdx.x * blockDim.x + threadIdx.x;
  int half = gid >> 19;
  int g = gid & ((1 << 19) - 1);
  int row = g >> 6, lane = g & 63;
  const float* src = half ? Y : X;
  unsigned short* dst = half ? Yb : Xb;
  float* dn = half ? Y2 : X2;
  const float* rp = src + (size_t)row * DIM + lane * 2;
  float a = rp[0], b = rp[1];
  __hip_bfloat16 ha = __float2bfloat16(a), hb = __float2bfloat16(b);
  unsigned short sa = *(unsigned short*)&ha, sb = *(unsigned short*)&hb;
  *(unsigned int*)(dst + (size_t)row * DIM + lane * 2) =
      (unsigned int)sa | ((unsigned int)sb << 16);
  float s = a * a + b * b;
  for (int off = 32; off; off >>= 1) s += __shfl_down(s, off, 64);
  if (lane == 0) dn[row] = s;
}

// ---- fused stripe-sweep: block = 128 rows x 512 cols; wave = 32 rows, A held in
// registers across the sweep; W never stored; R/C/Wmax partials out. ----
__global__ __launch_bounds__(256) void fused_sweep(const unsigned short* __restrict__ xb,
    const unsigned short* __restrict__ yb, const float* __restrict__ x2,
    const float* __restrict__ y2, float* __restrict__ Rpart, float* __restrict__ Cpart,
    float* __restrict__ wmaxp) {
  int bid = blockIdx.x;            // 1024 = 64 row-blocks x 16 chunks
  int bi = bid >> 4;               // row-block 0..63
  int ck = bid & 15;               // col-chunk 0..15
  int wv = threadIdx.x >> 6, lane = threadIdx.x & 63;
  int fr = lane & 15, fg = lane >> 4;
  int r0 = bi * 128 + wv * 32;     // this wave's 32 rows
  int band = bi * 4 + wv;          // Cpart band id

  // A fragments, held for the whole sweep: row r0+m*16+fr, k = kk*32+fg*8
  bf16x8 a[2][4];
  #pragma unroll
  for (int m = 0; m < 2; ++m)
    #pragma unroll
    for (int kk = 0; kk < 4; ++kk)
      a[m][kk] = *(const bf16x8*)(xb + (size_t)(r0 + m * 16 + fr) * DIM + kk * 32 + fg * 8);
  // xi for rows r0 + m*16 + fg*4 + r, vectorized over r
  f4 xi0 = *(const f4*)(x2 + r0 + fg * 4);
  f4 xi1 = *(const f4*)(x2 + r0 + 16 + fg * 4);

  float rs[2][4] = {{0.f,0.f,0.f,0.f},{0.f,0.f,0.f,0.f}};  // row partial (static idx)
  float wm = 0.f;

  for (int j = 0; j < 8; ++j) {
    int c0 = ck * 512 + j * 64;
    float y2v[4];
    #pragma unroll
    for (int n = 0; n < 4; ++n) y2v[n] = y2[c0 + n * 16 + fr];
    float cs[4] = {0.f, 0.f, 0.f, 0.f};
    #pragma unroll
    for (int h = 0; h < 2; ++h) {
      f32x4 acc[2][2];
      #pragma unroll
      for (int m = 0; m < 2; ++m)
        #pragma unroll
        for (int n2 = 0; n2 < 2; ++n2) acc[m][n2] = (f32x4){0.f, 0.f, 0.f, 0.f};
      #pragma unroll
      for (int kk = 0; kk < 4; ++kk) {
        bf16x8 b0 = *(const bf16x8*)(yb + (size_t)(c0 + (h * 2 + 0) * 16 + fr) * DIM + kk * 32 + fg * 8);
        bf16x8 b1 = *(const bf16x8*)(yb + (size_t)(c0 + (h * 2 + 1) * 16 + fr) * DIM + kk * 32 + fg * 8);
        acc[0][0] = __builtin_amdgcn_mfma_f32_16x16x32_bf16(a[0][kk], b0, acc[0][0], 0, 0, 0);
        acc[0][1] = __builtin_amdgcn_mfma_f32_16x16x32_bf16(a[0][kk], b1, acc[0][1], 0, 0, 0);
        acc[1][0] = __builtin_amdgcn_mfma_f32_16x16x32_bf16(a[1][kk], b0, acc[1][0], 0, 0, 0);
        acc[1][1] = __builtin_amdgcn_mfma_f32_16x16x32_bf16(a[1][kk], b1, acc[1][1], 0, 0, 0);
      }
      // epilogue: 16 elems/lane: i = r0+m*16+fg*4+r, jcol = c0+(h*2+n2)*16+fr
      #pragma unroll
      for (int m = 0; m < 2; ++m) {
        #pragma unroll
        for (int n2 = 0; n2 < 2; ++n2) {
          int n = h * 2 + n2;
          #pragma unroll
          for (int r = 0; r < 4; ++r) {
            float xi = (m == 0) ? xi0[r] : xi1[r];
            float d2 = xi + y2v[n] - 2.0f * acc[m][n2][r];
            float w = __builtin_amdgcn_sqrtf(fmaxf(d2, 0.f));
            wm = fmaxf(wm, w);
            rs[m][r] += w;
            cs[n] += w;
          }
        }
      }
    }
    // col partial: reduce over fg (rows within lane-groups), store per band
    #pragma unroll
    for (int n = 0; n < 4; ++n) {
      cs[n] += __shfl_xor(cs[n], 16, 64);
      cs[n] += __shfl_xor(cs[n], 32, 64);
      if (fg == 0) Cpart[(size_t)band * Mm + c0 + n * 16 + fr] = cs[n];
    }
  }

  // row partials: reduce across fr (the 16 col-lanes), once per sweep
  #pragma unroll
  for (int m = 0; m < 2; ++m)
    #pragma unroll
    for (int r = 0; r < 4; ++r) {
      rs[m][r] += __shfl_xor(rs[m][r], 1, 64);
      rs[m][r] += __shfl_xor(rs[m][r], 2, 64);
      rs[m][r] += __shfl_xor(rs[m][r], 4, 64);
      rs[m][r] += __shfl_xor(rs[m][r], 8, 64);
    }
  // writer lanes fr<8: (m,r) = (fr>>2, fr&3) via static cndmask chain
  float rv = rs[0][0];
  #pragma unroll
  for (int m = 0; m < 2; ++m)
    #pragma unroll
    for (int r = 0; r < 4; ++r)
      if (m | r) rv = (fr == m * 4 + r) ? rs[m][r] : rv;
  if (fr < 8)
    Rpart[(size_t)ck * Nn + r0 + (fr >> 2) * 16 + fg * 4 + (fr & 3)] = rv;

  // wave max -> block max
  #pragma unroll
  for (int mask = 1; mask < 64; mask <<= 1) wm = fmaxf(wm, __shfl_xor(wm, mask, 64));
  __shared__ float smax[4];
  if (lane == 0) smax[wv] = wm;
  __syncthreads();
  if (threadIdx.x == 0)
    wmaxp[bid] = fmaxf(fmaxf(smax[0], smax[1]), fmaxf(smax[2], smax[3]));
}

// ---- deterministic fixed-order reduction: rows sum 16 chunks, cols sum 256 bands ----
__global__ __launch_bounds__(256) void reduce_rc(const float* __restrict__ Rpart,
    const float* __restrict__ Cpart, double* __restrict__ Rd, double* __restrict__ Cd) {
  int t = blockIdx.x * blockDim.x + threadIdx.x;  // 16384 threads
  if (t < Nn) {
    double s = 0.0;
    #pragma unroll
    for (int k = 0; k < NCHUNK; ++k) s += (double)Rpart[(size_t)k * Nn + t];
    Rd[t] = s;
  } else {
    int c = t - Nn;
    double s = 0.0;
    for (int k = 0; k < NBAND; ++k) s += (double)Cpart[(size_t)k * Mm + c];
    Cd[c] = s;
  }
}

__device__ __forceinline__ double bred(double v, double* sb) {
  int tid = threadIdx.x;
  #pragma unroll
  for (int m = 1; m < 64; m <<= 1) v += __shfl_xor(v, m, 64);
  __syncthreads();
  if ((tid & 63) == 0) sb[tid >> 6] = v;
  __syncthreads();
  double s = (tid < 16) ? sb[tid] : 0.0;
  if (tid < 64) {
    #pragma unroll
    for (int m = 1; m < 16; m <<= 1) s += __shfl_xor(s, m, 16);
  }
  if (tid == 0) sb[0] = s;
  __syncthreads();
  return sb[0];
}

// ---- closed-form Sinkhorn from (R, C, Wmax); exact to fp32 resolution since
// K = 1 - cW with cW <= 7.8e-6. Convergence fires at it=1 (ref freeze). ----
__global__ __launch_bounds__(1024) void solve(const double* __restrict__ Rd,
    const double* __restrict__ Cd, const float* __restrict__ wmaxp,
    float* __restrict__ out) {
  __shared__ double sb[16];
  __shared__ float smx[16];
  int tid = threadIdx.x;
  float wl = wmaxp[tid];  // exactly 1024 partials
  #pragma unroll
  for (int m = 1; m < 64; m <<= 1) wl = fmaxf(wl, __shfl_xor(wl, m, 64));
  if ((tid & 63) == 0) smx[tid >> 6] = wl;
  __syncthreads();
  float wg = (tid < 16) ? smx[tid] : 0.f;
  if (tid < 64) {
    #pragma unroll
    for (int m = 1; m < 16; m <<= 1) wg = fmaxf(wg, __shfl_xor(wg, m, 16));
  }
  if (tid == 0) smx[0] = wg;
  __syncthreads();
  double wmax = (double)smx[0];
  double c = EPS / (128.0 * wmax);
  const double invm = 1.0 / 8192.0;
  double R[8], C[8];
  #pragma unroll
  for (int k = 0; k < 8; ++k) { R[k] = Rd[tid * 8 + k]; C[k] = Cd[tid * 8 + k]; }

  // it=0 u-update: S_v0 = 1 exactly
  double part = 0.0;
  #pragma unroll
  for (int k = 0; k < 8; ++k) part += 1.0 / (1.0 - c * invm * R[k]);
  double S_u1 = bred(part, sb);
  // it=0 v-update
  double cu1 = c * (S_u1 * invm);
  part = 0.0;
  #pragma unroll
  for (int k = 0; k < 8; ++k) part += 1.0 / (S_u1 - cu1 * C[k]);
  double S_v1 = bred(part, sb);
  // it=1 u-update (convergence fires here; v-update below still applies)
  double cv1 = c * (S_v1 * invm);
  double u2[8];
  part = 0.0;
  #pragma unroll
  for (int k = 0; k < 8; ++k) { u2[k] = 1.0 / (S_v1 - cv1 * R[k]); part += u2[k]; }
  double S_u2 = bred(part, sb);
  // it=1 v-update
  double cu2 = c * (S_u2 * invm);
  part = 0.0;
  #pragma unroll
  for (int k = 0; k < 8; ++k) part += 1.0 / (S_u2 - cu2 * C[k]);
  double S_v2 = bred(part, sb);
  // div = sum_i u2_i * (S_v2 - c*mean(v2)*R_i)
  double cv2 = c * (S_v2 * invm);
  part = 0.0;
  #pragma unroll
  for (int k = 0; k < 8; ++k) part += u2[k] * (S_v2 - cv2 * R[k]);
  double div = bred(part, sb);
  if (tid == 0) out[0] = (float)(div * invm);  // reduction='mean'
}

extern "C" void kernel_launch(void* const* d_in, const int* in_sizes, int n_in,
                              void* d_out, int out_size, void* d_ws, size_t ws_size,
                              hipStream_t stream) {
  const float* x = (const float*)d_in[0];
  const float* y = (const float*)d_in[1];
  char* ws = (char*)d_ws;
  size_t off = 0;
  unsigned short* xb = (unsigned short*)(ws + off); off += (size_t)Nn * DIM * 2;
  unsigned short* yb = (unsigned short*)(ws + off); off += (size_t)Mm * DIM * 2;
  float* x2 = (float*)(ws + off); off += (size_t)Nn * 4;
  float* y2 = (float*)(ws + off); off += (size_t)Mm * 4;
  float* Rpart = (float*)(ws + off); off += (size_t)NCHUNK * Nn * 4;   // 512 KiB
  float* Cpart = (float*)(ws + off); off += (size_t)NBAND * Mm * 4;    // 8 MiB
  double* Rd = (double*)(ws + off); off += (size_t)Nn * 8;
  double* Cd = (double*)(ws + off); off += (size_t)Mm * 8;
  float* wmaxp = (float*)(ws + off); off += 1024 * 4;

  prep2<<<4096, 256, 0, stream>>>(x, y, xb, yb, x2, y2);
  fused_sweep<<<1024, 256, 0, stream>>>(xb, yb, x2, y2, Rpart, Cpart, wmaxp);
  reduce_rc<<<64, 256, 0, stream>>>(Rpart, Cpart, Rd, Cd);
  solve<<<1, 1024, 0, stream>>>(Rd, Cd, wmaxp, (float*)d_out);
}

// Round 5
// 74.298 us; speedup vs baseline: 1.3602x; 1.3602x over previous
//
#include <hip/hip_runtime.h>
#include <hip/hip_bf16.h>
#include <math.h>

#define Nn 8192
#define Mm 8192
#define DIM 128
#define EPS 0.001
#define NCHUNK 16   // col chunks; each block sweeps 8 j-steps of 64 cols = 512 cols
#define NBAND 256   // 64 row-blocks x 4 waves

typedef __attribute__((ext_vector_type(8))) short bf16x8;
typedef __attribute__((ext_vector_type(4))) float f32x4;
typedef __attribute__((ext_vector_type(4))) float f4;
typedef __attribute__((ext_vector_type(4))) unsigned int u32x4;

__device__ __forceinline__ unsigned int pack2bf(float a, float b) {
  __hip_bfloat16 ha = __float2bfloat16(a), hb = __float2bfloat16(b);
  return (unsigned int)*(unsigned short*)&ha | ((unsigned int)*(unsigned short*)&hb << 16);
}

// ---- x prep: row-major bf16 + row squared-norms (A-fragment loads are one-time) ----
__global__ __launch_bounds__(256) void prep_x(const float* __restrict__ X,
    unsigned short* __restrict__ Xb, float* __restrict__ X2) {
  int gid = blockIdx.x * blockDim.x + threadIdx.x;   // 2048 blocks
  int row = gid >> 6, lane = gid & 63;
  const float* rp = X + (size_t)row * DIM + lane * 2;
  float a = rp[0], b = rp[1];
  *(unsigned int*)(Xb + (size_t)row * DIM + lane * 2) = pack2bf(a, b);
  float s = a * a + b * b;
  for (int off = 32; off; off >>= 1) s += __shfl_down(s, off, 64);
  if (lane == 0) X2[row] = s;
}

// ---- y prep: FRAGMENT-MAJOR bf16 so B-loads in the GEMM are lane-contiguous.
// Element (col = t*16+fr, k = kk*32+fg*8+s) -> Yf[t*2048 + kk*512 + (fg*16+fr)*8 + s].
// Thread = (row, kgroup g): reads 8 consecutive k (coalesced), writes one 16B slot. ----
__global__ __launch_bounds__(256) void prep_yf(const float* __restrict__ Y,
    unsigned short* __restrict__ Yf, float* __restrict__ Y2) {
  int gid = blockIdx.x * blockDim.x + threadIdx.x;   // 512 blocks -> 131072 threads
  int row = gid >> 4, g = gid & 15;
  f4 p0 = *(const f4*)(Y + (size_t)row * DIM + g * 8);
  f4 p1 = *(const f4*)(Y + (size_t)row * DIM + g * 8 + 4);
  u32x4 packed;
  packed[0] = pack2bf(p0[0], p0[1]);
  packed[1] = pack2bf(p0[2], p0[3]);
  packed[2] = pack2bf(p1[0], p1[1]);
  packed[3] = pack2bf(p1[2], p1[3]);
  int kk = g >> 2, fg = g & 3, t = row >> 4, fr = row & 15;
  size_t eoff = (size_t)t * 2048 + kk * 512 + (fg * 16 + fr) * 8;
  *(u32x4*)(Yf + eoff) = packed;
  float s = p0[0]*p0[0] + p0[1]*p0[1] + p0[2]*p0[2] + p0[3]*p0[3]
          + p1[0]*p1[0] + p1[1]*p1[1] + p1[2]*p1[2] + p1[3]*p1[3];
  s += __shfl_xor(s, 1, 64); s += __shfl_xor(s, 2, 64);
  s += __shfl_xor(s, 4, 64); s += __shfl_xor(s, 8, 64);
  if (g == 0) Y2[row] = s;
}

// ---- fused stripe-sweep: block = 128 rows x 512 cols; wave = 32 rows, A in regs;
// B-loads fully coalesced from fragment-major Yf; W never stored. ----
__global__ __launch_bounds__(256) void fused_sweep(const unsigned short* __restrict__ xb,
    const unsigned short* __restrict__ yf, const float* __restrict__ x2,
    const float* __restrict__ y2, float* __restrict__ Rpart, float* __restrict__ Cpart,
    float* __restrict__ wmaxp) {
  int bid = blockIdx.x;            // 1024 = 64 row-blocks x 16 chunks
  int bi = bid >> 4;               // row-block 0..63
  int ck = bid & 15;               // col-chunk 0..15
  int wv = threadIdx.x >> 6, lane = threadIdx.x & 63;
  int fr = lane & 15, fg = lane >> 4;
  int r0 = bi * 128 + wv * 32;     // this wave's 32 rows
  int band = bi * 4 + wv;          // Cpart band id

  // A fragments, held for the whole sweep (one-time strided loads)
  bf16x8 a[2][4];
  #pragma unroll
  for (int m = 0; m < 2; ++m)
    #pragma unroll
    for (int kk = 0; kk < 4; ++kk)
      a[m][kk] = *(const bf16x8*)(xb + (size_t)(r0 + m * 16 + fr) * DIM + kk * 32 + fg * 8);
  f4 xi0 = *(const f4*)(x2 + r0 + fg * 4);
  f4 xi1 = *(const f4*)(x2 + r0 + 16 + fg * 4);

  float rs[2][4] = {{0.f,0.f,0.f,0.f},{0.f,0.f,0.f,0.f}};
  float wm = 0.f;

  for (int j = 0; j < 8; ++j) {
    int c0 = ck * 512 + j * 64;
    int t0 = c0 >> 4;              // first of 4 n-tiles this step
    float y2v[4];
    #pragma unroll
    for (int n = 0; n < 4; ++n) y2v[n] = y2[c0 + n * 16 + fr];
    float cs[4] = {0.f, 0.f, 0.f, 0.f};
    #pragma unroll
    for (int h = 0; h < 2; ++h) {
      // coalesced: each load = base + lane*16B, contiguous 1KB per wave
      const unsigned short* p0 = yf + (size_t)(t0 + h * 2) * 2048 + lane * 8;
      const unsigned short* p1 = p0 + 2048;
      f32x4 acc[2][2];
      #pragma unroll
      for (int m = 0; m < 2; ++m)
        #pragma unroll
        for (int n2 = 0; n2 < 2; ++n2) acc[m][n2] = (f32x4){0.f, 0.f, 0.f, 0.f};
      #pragma unroll
      for (int kk = 0; kk < 4; ++kk) {
        bf16x8 b0 = *(const bf16x8*)(p0 + kk * 512);
        bf16x8 b1 = *(const bf16x8*)(p1 + kk * 512);
        acc[0][0] = __builtin_amdgcn_mfma_f32_16x16x32_bf16(a[0][kk], b0, acc[0][0], 0, 0, 0);
        acc[0][1] = __builtin_amdgcn_mfma_f32_16x16x32_bf16(a[0][kk], b1, acc[0][1], 0, 0, 0);
        acc[1][0] = __builtin_amdgcn_mfma_f32_16x16x32_bf16(a[1][kk], b0, acc[1][0], 0, 0, 0);
        acc[1][1] = __builtin_amdgcn_mfma_f32_16x16x32_bf16(a[1][kk], b1, acc[1][1], 0, 0, 0);
      }
      #pragma unroll
      for (int m = 0; m < 2; ++m) {
        #pragma unroll
        for (int n2 = 0; n2 < 2; ++n2) {
          int n = h * 2 + n2;
          #pragma unroll
          for (int r = 0; r < 4; ++r) {
            float xi = (m == 0) ? xi0[r] : xi1[r];
            float d2 = xi + y2v[n] - 2.0f * acc[m][n2][r];
            float w = __builtin_amdgcn_sqrtf(fmaxf(d2, 0.f));
            wm = fmaxf(wm, w);
            rs[m][r] += w;
            cs[n] += w;
          }
        }
      }
    }
    // col partial: reduce over fg, store per band
    #pragma unroll
    for (int n = 0; n < 4; ++n) {
      cs[n] += __shfl_xor(cs[n], 16, 64);
      cs[n] += __shfl_xor(cs[n], 32, 64);
      if (fg == 0) Cpart[(size_t)band * Mm + c0 + n * 16 + fr] = cs[n];
    }
  }

  // row partials: reduce across fr once per sweep
  #pragma unroll
  for (int m = 0; m < 2; ++m)
    #pragma unroll
    for (int r = 0; r < 4; ++r) {
      rs[m][r] += __shfl_xor(rs[m][r], 1, 64);
      rs[m][r] += __shfl_xor(rs[m][r], 2, 64);
      rs[m][r] += __shfl_xor(rs[m][r], 4, 64);
      rs[m][r] += __shfl_xor(rs[m][r], 8, 64);
    }
  float rv = rs[0][0];
  #pragma unroll
  for (int m = 0; m < 2; ++m)
    #pragma unroll
    for (int r = 0; r < 4; ++r)
      if (m | r) rv = (fr == m * 4 + r) ? rs[m][r] : rv;
  if (fr < 8)
    Rpart[(size_t)ck * Nn + r0 + (fr >> 2) * 16 + fg * 4 + (fr & 3)] = rv;

  #pragma unroll
  for (int mask = 1; mask < 64; mask <<= 1) wm = fmaxf(wm, __shfl_xor(wm, mask, 64));
  __shared__ float smax[4];
  if (lane == 0) smax[wv] = wm;
  __syncthreads();
  if (threadIdx.x == 0)
    wmaxp[bid] = fmaxf(fmaxf(smax[0], smax[1]), fmaxf(smax[2], smax[3]));
}

// ---- deterministic fixed-order reduction ----
__global__ __launch_bounds__(256) void reduce_rc(const float* __restrict__ Rpart,
    const float* __restrict__ Cpart, double* __restrict__ Rd, double* __restrict__ Cd) {
  int t = blockIdx.x * blockDim.x + threadIdx.x;  // 16384 threads
  if (t < Nn) {
    double s = 0.0;
    #pragma unroll
    for (int k = 0; k < NCHUNK; ++k) s += (double)Rpart[(size_t)k * Nn + t];
    Rd[t] = s;
  } else {
    int c = t - Nn;
    double s = 0.0;
    for (int k = 0; k < NBAND; ++k) s += (double)Cpart[(size_t)k * Mm + c];
    Cd[c] = s;
  }
}

__device__ __forceinline__ double bred(double v, double* sb) {
  int tid = threadIdx.x;
  #pragma unroll
  for (int m = 1; m < 64; m <<= 1) v += __shfl_xor(v, m, 64);
  __syncthreads();
  if ((tid & 63) == 0) sb[tid >> 6] = v;
  __syncthreads();
  double s = (tid < 16) ? sb[tid] : 0.0;
  if (tid < 64) {
    #pragma unroll
    for (int m = 1; m < 16; m <<= 1) s += __shfl_xor(s, m, 16);
  }
  if (tid == 0) sb[0] = s;
  __syncthreads();
  return sb[0];
}

// ---- closed-form Sinkhorn from (R, C, Wmax); exact to fp32 resolution since
// K = 1 - cW with cW <= 7.8e-6. Convergence fires at it=1 (ref freeze). ----
__global__ __launch_bounds__(1024) void solve(const double* __restrict__ Rd,
    const double* __restrict__ Cd, const float* __restrict__ wmaxp,
    float* __restrict__ out) {
  __shared__ double sb[16];
  __shared__ float smx[16];
  int tid = threadIdx.x;
  float wl = wmaxp[tid];  // exactly 1024 partials
  #pragma unroll
  for (int m = 1; m < 64; m <<= 1) wl = fmaxf(wl, __shfl_xor(wl, m, 64));
  if ((tid & 63) == 0) smx[tid >> 6] = wl;
  __syncthreads();
  float wg = (tid < 16) ? smx[tid] : 0.f;
  if (tid < 64) {
    #pragma unroll
    for (int m = 1; m < 16; m <<= 1) wg = fmaxf(wg, __shfl_xor(wg, m, 16));
  }
  if (tid == 0) smx[0] = wg;
  __syncthreads();
  double wmax = (double)smx[0];
  double c = EPS / (128.0 * wmax);
  const double invm = 1.0 / 8192.0;
  double R[8], C[8];
  #pragma unroll
  for (int k = 0; k < 8; ++k) { R[k] = Rd[tid * 8 + k]; C[k] = Cd[tid * 8 + k]; }

  double part = 0.0;
  #pragma unroll
  for (int k = 0; k < 8; ++k) part += 1.0 / (1.0 - c * invm * R[k]);
  double S_u1 = bred(part, sb);
  double cu1 = c * (S_u1 * invm);
  part = 0.0;
  #pragma unroll
  for (int k = 0; k < 8; ++k) part += 1.0 / (S_u1 - cu1 * C[k]);
  double S_v1 = bred(part, sb);
  double cv1 = c * (S_v1 * invm);
  double u2[8];
  part = 0.0;
  #pragma unroll
  for (int k = 0; k < 8; ++k) { u2[k] = 1.0 / (S_v1 - cv1 * R[k]); part += u2[k]; }
  double S_u2 = bred(part, sb);
  double cu2 = c * (S_u2 * invm);
  part = 0.0;
  #pragma unroll
  for (int k = 0; k < 8; ++k) part += 1.0 / (S_u2 - cu2 * C[k]);
  double S_v2 = bred(part, sb);
  double cv2 = c * (S_v2 * invm);
  part = 0.0;
  #pragma unroll
  for (int k = 0; k < 8; ++k) part += u2[k] * (S_v2 - cv2 * R[k]);
  double div = bred(part, sb);
  if (tid == 0) out[0] = (float)(div * invm);  // reduction='mean'
}

extern "C" void kernel_launch(void* const* d_in, const int* in_sizes, int n_in,
                              void* d_out, int out_size, void* d_ws, size_t ws_size,
                              hipStream_t stream) {
  const float* x = (const float*)d_in[0];
  const float* y = (const float*)d_in[1];
  char* ws = (char*)d_ws;
  size_t off = 0;
  unsigned short* xb = (unsigned short*)(ws + off); off += (size_t)Nn * DIM * 2;
  unsigned short* yf = (unsigned short*)(ws + off); off += (size_t)Mm * DIM * 2;
  float* x2 = (float*)(ws + off); off += (size_t)Nn * 4;
  float* y2 = (float*)(ws + off); off += (size_t)Mm * 4;
  float* Rpart = (float*)(ws + off); off += (size_t)NCHUNK * Nn * 4;
  float* Cpart = (float*)(ws + off); off += (size_t)NBAND * Mm * 4;
  double* Rd = (double*)(ws + off); off += (size_t)Nn * 8;
  double* Cd = (double*)(ws + off); off += (size_t)Mm * 8;
  float* wmaxp = (float*)(ws + off); off += 1024 * 4;

  prep_x<<<2048, 256, 0, stream>>>(x, xb, x2);
  prep_yf<<<512, 256, 0, stream>>>(y, yf, y2);
  fused_sweep<<<1024, 256, 0, stream>>>(xb, yf, x2, y2, Rpart, Cpart, wmaxp);
  reduce_rc<<<64, 256, 0, stream>>>(Rpart, Cpart, Rd, Cd);
  solve<<<1, 1024, 0, stream>>>(Rd, Cd, wmaxp, (float*)d_out);
}